// Round 10
// baseline (1361.393 us; speedup 1.0000x reference)
//
#include <hip/hip_runtime.h>
#include <math.h>

#define BS   2048
#define DIM  2048
#define NE   64
#define NF   512
#define TOPK 8
#define MAXT 320   // max (expert, m0) tiles: sum ceil(n_e/64) <= 256+64

typedef __attribute__((ext_vector_type(8))) short bf16x8;
typedef __attribute__((ext_vector_type(4))) float f32x4;

// pack 2 f32 -> 2 bf16 (RNE), lo in [15:0]
__device__ __forceinline__ unsigned cvt2(float lo, float hi) {
    unsigned r;
    asm("v_cvt_pk_bf16_f32 %0, %1, %2" : "=v"(r) : "v"(lo), "v"(hi));
    return r;
}
__device__ __forceinline__ unsigned short f2bf(float f) {
    return (unsigned short)(cvt2(f, 0.f) & 0xFFFF);
}

// swizzled LDS addressing: 64-col bf16 rows (128 B), XOR bits 4-6 with row&7
#define SWZ(r, b) (((((r) << 7) + (b)) ^ (((r) & 7) << 4)))

// ---------------- zero out + counters ----------------
__global__ __launch_bounds__(256) void zero_kernel(float* __restrict__ out, int* __restrict__ count)
{
    const size_t idx = (size_t)blockIdx.x * blockDim.x + threadIdx.x;
    const size_t tot = (size_t)BS * DIM;
    for (size_t i = idx * 4; i < tot; i += (size_t)gridDim.x * blockDim.x * 4) {
        *(float4*)&out[i] = make_float4(0.f, 0.f, 0.f, 0.f);
    }
    if (idx < NE) count[idx] = 0;
}

// ---------------- x fp32 -> bf16 (8.4 MB, L3-resident working copy) ----------------
__global__ __launch_bounds__(256) void cvt_x_kernel(const float* __restrict__ x,
                                                    unsigned short* __restrict__ xb)
{
    const int idx = blockIdx.x * 256 + threadIdx.x;
    const int tot = BS * DIM / 4;
    for (int i = idx; i < tot; i += gridDim.x * 256) {
        const float4 v = *(const float4*)&x[i * 4];
        *(uint2*)&xb[i * 4] = make_uint2(cvt2(v.x, v.y), cvt2(v.z, v.w));
    }
}

// ---------------- router: 4 tokens/block, wave-parallel top-8 ----------------
__global__ __launch_bounds__(256) void router_kernel(
    const float* __restrict__ x, const float* __restrict__ gate_w,
    const int* __restrict__ token_mod, const int* __restrict__ expert_mod,
    int* __restrict__ count, int* __restrict__ list_token, float* __restrict__ list_w)
{
    __shared__ float xs[4 * DIM];
    __shared__ float pr[4][NE];
    const int t0  = blockIdx.x * 4;
    const int tid = threadIdx.x;
    const int lane = tid & 63, wave = tid >> 6;

    float4* xs4 = (float4*)xs;
    const float4* xr = (const float4*)(x + (size_t)t0 * DIM);
    for (int i = tid; i < 4 * (DIM / 4); i += 256) xs4[i] = xr[i];
    __syncthreads();

    for (int j = 0; j < 16; ++j) {
        const int e = wave * 16 + j;
        const float4* gw = (const float4*)(gate_w + (size_t)e * DIM);
        float s0 = 0.f, s1 = 0.f, s2 = 0.f, s3 = 0.f;
        for (int i = lane; i < DIM / 4; i += 64) {
            const float4 g  = gw[i];
            const float4 v0 = xs4[0 * 512 + i];
            const float4 v1 = xs4[1 * 512 + i];
            const float4 v2 = xs4[2 * 512 + i];
            const float4 v3 = xs4[3 * 512 + i];
            s0 += v0.x * g.x + v0.y * g.y + v0.z * g.z + v0.w * g.w;
            s1 += v1.x * g.x + v1.y * g.y + v1.z * g.z + v1.w * g.w;
            s2 += v2.x * g.x + v2.y * g.y + v2.z * g.z + v2.w * g.w;
            s3 += v3.x * g.x + v3.y * g.y + v3.z * g.z + v3.w * g.w;
        }
        #pragma unroll
        for (int off = 32; off > 0; off >>= 1) {
            s0 += __shfl_xor(s0, off, 64);
            s1 += __shfl_xor(s1, off, 64);
            s2 += __shfl_xor(s2, off, 64);
            s3 += __shfl_xor(s3, off, 64);
        }
        if (lane == 0) {
            pr[0][e] = s0; pr[1][e] = s1; pr[2][e] = s2; pr[3][e] = s3;
        }
    }
    __syncthreads();

    {
        const int t  = t0 + wave;
        const int tm = token_mod[t];
        const int em = expert_mod[lane];
        float p = pr[wave][lane];
        if (tm * em == -1) p = -INFINITY;
        float m0 = p;
        #pragma unroll
        for (int off = 32; off > 0; off >>= 1) m0 = fmaxf(m0, __shfl_xor(m0, off, 64));
        p = __expf(p - m0);                  // exp(-inf)=0; softmax denom cancels in renorm
        float s8 = 0.f, wsel = 0.f;
        int   esel = 0;
        #pragma unroll
        for (int k = 0; k < TOPK; ++k) {
            float m = p;
            #pragma unroll
            for (int off = 32; off > 0; off >>= 1) m = fmaxf(m, __shfl_xor(m, off, 64));
            const unsigned long long b = __ballot(p == m);
            const int bi = __ffsll((unsigned long long)b) - 1;   // lowest index on ties
            if (lane == bi) p = -1.f;
            if (lane == k) { esel = bi; wsel = m; }
            s8 += m;
        }
        const float inv = 1.f / s8;
        if (lane < TOPK) {
            const int pos = atomicAdd(&count[esel], 1);
            list_token[esel * BS + pos] = t;
            list_w[esel * BS + pos]     = wsel * inv;
        }
    }
}

// ---------------- scan + compacted (expert, m0) worklist ----------------
__global__ void scan_kernel(const int* __restrict__ count, int* __restrict__ offsets,
                            int* __restrict__ worklist, int* __restrict__ ntiles)
{
    if (threadIdx.x == 0) {
        int s = 0, nt = 0;
        for (int e = 0; e < NE; ++e) {
            offsets[e] = s;
            for (int m0 = 0; m0 < count[e]; m0 += 64) worklist[nt++] = (e << 16) | m0;
            s += count[e];
        }
        ntiles[0] = nt;
    }
}

// ================= gate/up MFMA GEMM: single-buffer LDS, 2-deep reg prefetch =================
// block 64 tok x 64 f, BK=64, 32 steps. 4 waves; wave = 32 tok x 32 f (gate+up).
// LDS 24KB single buffer. Raw s_barrier (NO vmcnt drain) keeps both prefetch sets in flight.
// MFMA operands: A = weights (f rows), B = X (token rows) -> C rows = f: uint2 h-stores.
#define GU_X   0
#define GU_G   8192
#define GU_U   16384
#define GU_NST 32

#define GU_ISSUE(S, KO)                                                       \
    {                                                                         \
        _Pragma("unroll")                                                     \
        for (int i = 0; i < 2; ++i) lxx##S[i] = *(const uint4*)(xrow[i] + (KO)); \
        _Pragma("unroll")                                                     \
        for (int i = 0; i < 4; ++i) {                                         \
            lg##S[i] = *(const float4*)(grow[i] + (KO));                      \
            lu##S[i] = *(const float4*)(urow[i] + (KO));                      \
        }                                                                     \
    }

#define GU_LDSW(S)                                                            \
    {                                                                         \
        _Pragma("unroll")                                                     \
        for (int i = 0; i < 2; ++i)                                           \
            *(uint4*)&lds[GU_X + SWZ(xr0 + i * 32, xb0 * 16)] = lxx##S[i];    \
        _Pragma("unroll")                                                     \
        for (int i = 0; i < 4; ++i) {                                         \
            const int r = rr + i * 16;                                        \
            *(uint2*)&lds[GU_G + SWZ(r, c4 * 8)] = make_uint2(cvt2(lg##S[i].x, lg##S[i].y), cvt2(lg##S[i].z, lg##S[i].w)); \
            *(uint2*)&lds[GU_U + SWZ(r, c4 * 8)] = make_uint2(cvt2(lu##S[i].x, lu##S[i].y), cvt2(lu##S[i].z, lu##S[i].w)); \
        }                                                                     \
    }

#define GU_COMPUTE()                                                          \
    {                                                                         \
        _Pragma("unroll")                                                     \
        for (int ks = 0; ks < 2; ++ks) {                                      \
            const int kb = (ks * 32 + (lane >> 4) * 8) * 2;                   \
            bf16x8 bx[2], ag[2], au[2];                                       \
            _Pragma("unroll")                                                 \
            for (int nt = 0; nt < 2; ++nt)                                    \
                bx[nt] = *(const bf16x8*)&lds[GU_X + SWZ(wr * 32 + nt * 16 + (lane & 15), kb)]; \
            _Pragma("unroll")                                                 \
            for (int mm = 0; mm < 2; ++mm) {                                  \
                const int r = wc * 32 + mm * 16 + (lane & 15);                \
                ag[mm] = *(const bf16x8*)&lds[GU_G + SWZ(r, kb)];             \
                au[mm] = *(const bf16x8*)&lds[GU_U + SWZ(r, kb)];             \
            }                                                                 \
            _Pragma("unroll")                                                 \
            for (int mm = 0; mm < 2; ++mm)                                    \
                _Pragma("unroll")                                             \
                for (int nt = 0; nt < 2; ++nt) {                              \
                    accg[mm][nt] = __builtin_amdgcn_mfma_f32_16x16x32_bf16(ag[mm], bx[nt], accg[mm][nt], 0, 0, 0); \
                    accu[mm][nt] = __builtin_amdgcn_mfma_f32_16x16x32_bf16(au[mm], bx[nt], accu[mm][nt], 0, 0, 0); \
                }                                                             \
        }                                                                     \
    }

#define GU_SYNC_W()                                                           \
    asm volatile("s_waitcnt lgkmcnt(0)" ::: "memory");                        \
    __builtin_amdgcn_sched_barrier(0);                                        \
    __builtin_amdgcn_s_barrier();

__global__ __launch_bounds__(256, 3) void gateup_mfma(
    const unsigned short* __restrict__ xb,
    const float* __restrict__ w_gate, const float* __restrict__ w_up,
    const int* __restrict__ count, const int* __restrict__ offsets,
    const int* __restrict__ worklist, const int* __restrict__ ntiles,
    const int* __restrict__ list_token, const float* __restrict__ list_w,
    unsigned short* __restrict__ h)
{
    if ((int)blockIdx.y >= ntiles[0]) return;
    const int wl = worklist[blockIdx.y];
    const int e  = wl >> 16;
    const int m0 = wl & 0xFFFF;
    const int f0 = blockIdx.x * 64;
    const int mc = min(64, count[e] - m0);

    __shared__ char  lds[24576];
    __shared__ int   toks[64];
    __shared__ float rws[64];

    const int tid = threadIdx.x;
    if (tid < 64) {
        const int idx = e * BS + m0 + (tid < mc ? tid : 0);
        toks[tid] = list_token[idx];
        rws[tid]  = (tid < mc) ? list_w[idx] : 0.f;
    }
    __syncthreads();

    const int lane = tid & 63, wave = tid >> 6;
    const int wr = wave >> 1, wc = wave & 1;
    const int rr = tid >> 4;          // 0..15 (G/U staging row base)
    const int c4 = tid & 15;          // float4 col (16 per 64-float row)
    const int xr0 = tid >> 3;         // 0..31 (X staging rows xr0, xr0+32)
    const int xb0 = tid & 7;          // 16B block within 128B bf16 row

    const unsigned short* xrow[2];
    #pragma unroll
    for (int i = 0; i < 2; ++i)
        xrow[i] = xb + (size_t)toks[xr0 + i * 32] * DIM + xb0 * 8;
    const float* grow[4];
    const float* urow[4];
    #pragma unroll
    for (int i = 0; i < 4; ++i) {
        grow[i] = w_gate + (size_t)e * NF * DIM + (size_t)(f0 + rr + i * 16) * DIM + c4 * 4;
        urow[i] = w_up   + (size_t)e * NF * DIM + (size_t)(f0 + rr + i * 16) * DIM + c4 * 4;
    }

    f32x4 accg[2][2] = {};
    f32x4 accu[2][2] = {};
    uint4  lxxE[2], lxxO[2];
    float4 lgE[4], luE[4], lgO[4], luO[4];

    // prologue: tiles 0 (E) and 1 (O) in flight; write tile 0
    GU_ISSUE(E, 0);
    GU_ISSUE(O, 64);
    __builtin_amdgcn_sched_barrier(0);
    GU_LDSW(E);                      // auto-counted vmcnt (O still in flight)
    GU_SYNC_W();

    for (int t = 0; t < GU_NST; t += 2) {
        if (t + 2 < GU_NST) { GU_ISSUE(E, (t + 2) * 64); __builtin_amdgcn_sched_barrier(0); }
        GU_COMPUTE();                                    // tile t
        __builtin_amdgcn_sched_barrier(0);
        __builtin_amdgcn_s_barrier();                    // reads done (no vm drain)
        GU_LDSW(O);                                      // tile t+1 -> LDS
        GU_SYNC_W();
        if (t + 3 < GU_NST) { GU_ISSUE(O, (t + 3) * 64); __builtin_amdgcn_sched_barrier(0); }
        GU_COMPUTE();                                    // tile t+1
        if (t + 2 < GU_NST) {
            __builtin_amdgcn_sched_barrier(0);
            __builtin_amdgcn_s_barrier();
            GU_LDSW(E);                                  // tile t+2 -> LDS
            GU_SYNC_W();
        }
    }

    const int base = offsets[e] + m0;
    #pragma unroll
    for (int mm = 0; mm < 2; ++mm) {
        #pragma unroll
        for (int nt = 0; nt < 2; ++nt) {
            const int tl = wr * 32 + nt * 16 + (lane & 15);
            if (tl < mc) {
                const float w = rws[tl];
                float hv[4];
                #pragma unroll
                for (int j = 0; j < 4; ++j) {
                    const float g = accg[mm][nt][j];
                    const float u = accu[mm][nt][j];
                    hv[j] = w * u * (g / (1.f + __expf(-g)));
                }
                const int fl = f0 + wc * 32 + mm * 16 + (lane >> 4) * 4;
                *(uint2*)&h[(size_t)(base + tl) * NF + fl] =
                    make_uint2(cvt2(hv[0], hv[1]), cvt2(hv[2], hv[3]));
            }
        }
    }
}

// ================= down MFMA GEMM: same pipeline + atomic combine =================
// block 64 slots x 128 d, BK=64 over F=512 (8 steps). wave = 32 slots x 64 d.
// A = w_down (d rows), B = H (slot rows) -> C rows = d: 4 consecutive-addr atomics.
#define DK_H   0
#define DK_W   8192
#define DK_NST 8

#define DK_ISSUE(S, KO)                                                       \
    {                                                                         \
        _Pragma("unroll")                                                     \
        for (int i = 0; i < 2; ++i) lh##S[i] = *(const uint4*)(hrow[i] + (KO)); \
        _Pragma("unroll")                                                     \
        for (int i = 0; i < 8; ++i) lw##S[i] = *(const float4*)(wrow[i] + (KO)); \
    }

#define DK_LDSW(S)                                                            \
    {                                                                         \
        _Pragma("unroll")                                                     \
        for (int i = 0; i < 2; ++i)                                           \
            *(uint4*)&lds[DK_H + SWZ(hr + i * 32, hc * 2)] = lh##S[i];        \
        _Pragma("unroll")                                                     \
        for (int i = 0; i < 8; ++i)                                           \
            *(uint2*)&lds[DK_W + SWZ(rr + i * 16, c4 * 8)] = make_uint2(cvt2(lw##S[i].x, lw##S[i].y), cvt2(lw##S[i].z, lw##S[i].w)); \
    }

#define DK_COMPUTE()                                                          \
    {                                                                         \
        _Pragma("unroll")                                                     \
        for (int ks = 0; ks < 2; ++ks) {                                      \
            const int kb = (ks * 32 + (lane >> 4) * 8) * 2;                   \
            bf16x8 bh[2], aw[4];                                              \
            _Pragma("unroll")                                                 \
            for (int nt = 0; nt < 2; ++nt)                                    \
                bh[nt] = *(const bf16x8*)&lds[DK_H + SWZ(wr * 32 + nt * 16 + (lane & 15), kb)]; \
            _Pragma("unroll")                                                 \
            for (int dd = 0; dd < 4; ++dd)                                    \
                aw[dd] = *(const bf16x8*)&lds[DK_W + SWZ(wc * 64 + dd * 16 + (lane & 15), kb)]; \
            _Pragma("unroll")                                                 \
            for (int dd = 0; dd < 4; ++dd)                                    \
                _Pragma("unroll")                                             \
                for (int nt = 0; nt < 2; ++nt)                                \
                    acc[dd][nt] = __builtin_amdgcn_mfma_f32_16x16x32_bf16(aw[dd], bh[nt], acc[dd][nt], 0, 0, 0); \
        }                                                                     \
    }

__global__ __launch_bounds__(256, 3) void down_mfma(
    const float* __restrict__ w_down,
    const int* __restrict__ count, const int* __restrict__ offsets,
    const int* __restrict__ worklist, const int* __restrict__ ntiles,
    const int* __restrict__ list_token,
    const unsigned short* __restrict__ h, float* __restrict__ out)
{
    if ((int)blockIdx.y >= ntiles[0]) return;
    const int wl = worklist[blockIdx.y];
    const int e  = wl >> 16;
    const int m0 = wl & 0xFFFF;
    const int d0 = blockIdx.x * 128;
    const int mc = min(64, count[e] - m0);

    __shared__ char lds[24576];
    __shared__ int  toks[64];

    const int tid = threadIdx.x;
    if (tid < 64) toks[tid] = list_token[e * BS + m0 + (tid < mc ? tid : 0)];
    __syncthreads();

    const int lane = tid & 63, wave = tid >> 6;
    const int wr = wave >> 1, wc = wave & 1;
    const int rr = tid >> 4;          // 0..15 (W rows)
    const int c4 = tid & 15;          // float4 col
    const int hr = tid >> 3;          // 0..31 (H rows)
    const int hc = (tid & 7) * 8;     // bf16 col (8 per 16B)

    const float* wd  = w_down + (size_t)e * DIM * NF;
    const int   base = offsets[e] + m0;

    const unsigned short* hrow[2];
    #pragma unroll
    for (int i = 0; i < 2; ++i) {
        const int r  = hr + i * 32;
        const int rs = (r < mc ? r : 0);
        hrow[i] = h + (size_t)(base + rs) * NF + hc;
    }
    const float* wrow[8];
    #pragma unroll
    for (int i = 0; i < 8; ++i) wrow[i] = wd + (size_t)(d0 + rr + i * 16) * NF + c4 * 4;

    f32x4 acc[4][2] = {};
    uint4  lhE[2], lhO[2];
    float4 lwE[8], lwO[8];

    DK_ISSUE(E, 0);
    DK_ISSUE(O, 64);
    __builtin_amdgcn_sched_barrier(0);
    DK_LDSW(E);
    GU_SYNC_W();

    for (int t = 0; t < DK_NST; t += 2) {
        if (t + 2 < DK_NST) { DK_ISSUE(E, (t + 2) * 64); __builtin_amdgcn_sched_barrier(0); }
        DK_COMPUTE();
        __builtin_amdgcn_sched_barrier(0);
        __builtin_amdgcn_s_barrier();
        DK_LDSW(O);
        GU_SYNC_W();
        if (t + 3 < DK_NST) { DK_ISSUE(O, (t + 3) * 64); __builtin_amdgcn_sched_barrier(0); }
        DK_COMPUTE();
        if (t + 2 < DK_NST) {
            __builtin_amdgcn_sched_barrier(0);
            __builtin_amdgcn_s_barrier();
            DK_LDSW(E);
            GU_SYNC_W();
        }
    }

    #pragma unroll
    for (int dd = 0; dd < 4; ++dd)
        #pragma unroll
        for (int nt = 0; nt < 2; ++nt) {
            const int tl = wr * 32 + nt * 16 + (lane & 15);
            if (tl < mc) {
                const int tok = toks[tl];
                float* orow = out + (size_t)tok * DIM + d0 + wc * 64 + dd * 16 + (lane >> 4) * 4;
                #pragma unroll
                for (int j = 0; j < 4; ++j)
                    atomicAdd(&orow[j], acc[dd][nt][j]);
            }
        }
}

extern "C" void kernel_launch(void* const* d_in, const int* in_sizes, int n_in,
                              void* d_out, int out_size, void* d_ws, size_t ws_size,
                              hipStream_t stream)
{
    const float* x          = (const float*)d_in[0];
    const float* gate_w     = (const float*)d_in[1];
    const float* w_gate     = (const float*)d_in[2];
    const float* w_up       = (const float*)d_in[3];
    const float* w_down     = (const float*)d_in[4];
    const int*   token_mod  = (const int*)d_in[5];
    const int*   expert_mod = (const int*)d_in[6];
    float* out = (float*)d_out;

    // ws: h bf16 16 MB | x_bf16 8 MB | count | offsets | ntiles | worklist | list_token | list_w
    char* ws = (char*)d_ws;
    unsigned short* h  = (unsigned short*)ws;                       // 16,777,216 B
    unsigned short* xb = (unsigned short*)(ws + 16777216);          //  8,388,608 B
    int*   count      = (int*)(ws + 25165824);                      // 256 B
    int*   offsets    = (int*)(ws + 25166080);                      // 256 B
    int*   ntiles     = (int*)(ws + 25166336);                      // 256 B
    int*   worklist   = (int*)(ws + 25166592);                      // 2048 B
    int*   list_token = (int*)(ws + 25168640);                      // 524,288 B
    float* list_w     = (float*)(ws + 25692928);                    // 524,288 B

    zero_kernel<<<2048, 256, 0, stream>>>(out, count);
    cvt_x_kernel<<<1024, 256, 0, stream>>>(x, xb);
    router_kernel<<<BS / 4, 256, 0, stream>>>(x, gate_w, token_mod, expert_mod,
                                              count, list_token, list_w);
    scan_kernel<<<1, 64, 0, stream>>>(count, offsets, worklist, ntiles);

    dim3 g1(NF / 64, MAXT);    // (8, 320)
    gateup_mfma<<<g1, 256, 0, stream>>>(xb, w_gate, w_up, count, offsets,
                                        worklist, ntiles, list_token, list_w, h);
    dim3 g2(DIM / 128, MAXT);  // (16, 320)
    down_mfma<<<g2, 256, 0, stream>>>(w_down, count, offsets, worklist, ntiles,
                                      list_token, h, out);
}

// Round 11
// 1127.513 us; speedup vs baseline: 1.2074x; 1.2074x over previous
//
#include <hip/hip_runtime.h>
#include <math.h>

#define BS   2048
#define DIM  2048
#define NE   64
#define NF   512
#define TOPK 8
#define NT32 576   // max (expert, m0) 32-token tiles: 16384/32 + 64

typedef __attribute__((ext_vector_type(8))) short bf16x8;
typedef __attribute__((ext_vector_type(4))) float f32x4;

// pack 2 f32 -> 2 bf16 (RNE), lo in [15:0]
__device__ __forceinline__ unsigned cvt2(float lo, float hi) {
    unsigned r;
    asm("v_cvt_pk_bf16_f32 %0, %1, %2" : "=v"(r) : "v"(lo), "v"(hi));
    return r;
}
// 8 fp32 (two float4) -> bf16x8 fragment
__device__ __forceinline__ bf16x8 pk8(float4 lo, float4 hi) {
    union { bf16x8 v; unsigned u[4]; } r;
    r.u[0] = cvt2(lo.x, lo.y); r.u[1] = cvt2(lo.z, lo.w);
    r.u[2] = cvt2(hi.x, hi.y); r.u[3] = cvt2(hi.z, hi.w);
    return r.v;
}
__device__ __forceinline__ unsigned short f2bf(float f) {
    return (unsigned short)(cvt2(f, 0.f) & 0xFFFF);
}

// ---------------- zero out + counters ----------------
__global__ __launch_bounds__(256) void zero_kernel(float* __restrict__ out, int* __restrict__ count)
{
    const size_t idx = (size_t)blockIdx.x * blockDim.x + threadIdx.x;
    const size_t tot = (size_t)BS * DIM;
    for (size_t i = idx * 4; i < tot; i += (size_t)gridDim.x * blockDim.x * 4) {
        *(float4*)&out[i] = make_float4(0.f, 0.f, 0.f, 0.f);
    }
    if (idx < NE) count[idx] = 0;
}

// ---------------- x fp32 -> bf16 (8.4 MB, L3-resident working copy) ----------------
__global__ __launch_bounds__(256) void cvt_x_kernel(const float* __restrict__ x,
                                                    unsigned short* __restrict__ xb)
{
    const int idx = blockIdx.x * 256 + threadIdx.x;
    const int tot = BS * DIM / 4;
    for (int i = idx; i < tot; i += gridDim.x * 256) {
        const float4 v = *(const float4*)&x[i * 4];
        *(uint2*)&xb[i * 4] = make_uint2(cvt2(v.x, v.y), cvt2(v.z, v.w));
    }
}

// ---------------- router: 4 tokens/block, wave-parallel top-8 ----------------
__global__ __launch_bounds__(256) void router_kernel(
    const float* __restrict__ x, const float* __restrict__ gate_w,
    const int* __restrict__ token_mod, const int* __restrict__ expert_mod,
    int* __restrict__ count, int* __restrict__ list_token, float* __restrict__ list_w)
{
    __shared__ float xs[4 * DIM];
    __shared__ float pr[4][NE];
    const int t0  = blockIdx.x * 4;
    const int tid = threadIdx.x;
    const int lane = tid & 63, wave = tid >> 6;

    float4* xs4 = (float4*)xs;
    const float4* xr = (const float4*)(x + (size_t)t0 * DIM);
    for (int i = tid; i < 4 * (DIM / 4); i += 256) xs4[i] = xr[i];
    __syncthreads();

    for (int j = 0; j < 16; ++j) {
        const int e = wave * 16 + j;
        const float4* gw = (const float4*)(gate_w + (size_t)e * DIM);
        float s0 = 0.f, s1 = 0.f, s2 = 0.f, s3 = 0.f;
        for (int i = lane; i < DIM / 4; i += 64) {
            const float4 g  = gw[i];
            const float4 v0 = xs4[0 * 512 + i];
            const float4 v1 = xs4[1 * 512 + i];
            const float4 v2 = xs4[2 * 512 + i];
            const float4 v3 = xs4[3 * 512 + i];
            s0 += v0.x * g.x + v0.y * g.y + v0.z * g.z + v0.w * g.w;
            s1 += v1.x * g.x + v1.y * g.y + v1.z * g.z + v1.w * g.w;
            s2 += v2.x * g.x + v2.y * g.y + v2.z * g.z + v2.w * g.w;
            s3 += v3.x * g.x + v3.y * g.y + v3.z * g.z + v3.w * g.w;
        }
        #pragma unroll
        for (int off = 32; off > 0; off >>= 1) {
            s0 += __shfl_xor(s0, off, 64);
            s1 += __shfl_xor(s1, off, 64);
            s2 += __shfl_xor(s2, off, 64);
            s3 += __shfl_xor(s3, off, 64);
        }
        if (lane == 0) {
            pr[0][e] = s0; pr[1][e] = s1; pr[2][e] = s2; pr[3][e] = s3;
        }
    }
    __syncthreads();

    {
        const int t  = t0 + wave;
        const int tm = token_mod[t];
        const int em = expert_mod[lane];
        float p = pr[wave][lane];
        if (tm * em == -1) p = -INFINITY;
        float m0 = p;
        #pragma unroll
        for (int off = 32; off > 0; off >>= 1) m0 = fmaxf(m0, __shfl_xor(m0, off, 64));
        p = __expf(p - m0);                  // exp(-inf)=0; softmax denom cancels in renorm
        float s8 = 0.f, wsel = 0.f;
        int   esel = 0;
        #pragma unroll
        for (int k = 0; k < TOPK; ++k) {
            float m = p;
            #pragma unroll
            for (int off = 32; off > 0; off >>= 1) m = fmaxf(m, __shfl_xor(m, off, 64));
            const unsigned long long b = __ballot(p == m);
            const int bi = __ffsll((unsigned long long)b) - 1;   // lowest index on ties
            if (lane == bi) p = -1.f;
            if (lane == k) { esel = bi; wsel = m; }
            s8 += m;
        }
        const float inv = 1.f / s8;
        if (lane < TOPK) {
            const int pos = atomicAdd(&count[esel], 1);
            list_token[esel * BS + pos] = t;
            list_w[esel * BS + pos]     = wsel * inv;
        }
    }
}

// ---------------- scan + compacted (expert, m0) 32-token worklist ----------------
__global__ void scan_kernel(const int* __restrict__ count, int* __restrict__ offsets,
                            int* __restrict__ worklist, int* __restrict__ ntiles)
{
    if (threadIdx.x == 0) {
        int s = 0, nt = 0;
        for (int e = 0; e < NE; ++e) {
            offsets[e] = s;
            for (int m0 = 0; m0 < count[e]; m0 += 32) worklist[nt++] = (e << 16) | m0;
            s += count[e];
        }
        ntiles[0] = nt;
    }
}

// ================= gate/up: 1-wave blocks, direct-to-reg streaming MFMA =================
// wave tile = 32 tok x 32 f (gate AND up), BK=32, 64 steps. No LDS, no barriers.
// E/O 1-deep prefetch pinned with sched_barrier (R7-proven). ~12 independent waves/CU.

#define GU_ISSUE(S, KO)                                                       \
    {                                                                         \
        _Pragma("unroll")                                                     \
        for (int m = 0; m < 2; ++m) a##S[m] = *(const bf16x8*)(aptr[m] + (KO)); \
        _Pragma("unroll")                                                     \
        for (int n = 0; n < 2; ++n) {                                         \
            g##S[n * 2]     = *(const float4*)(gp[n] + (KO));                 \
            g##S[n * 2 + 1] = *(const float4*)(gp[n] + (KO) + 4);             \
            u##S[n * 2]     = *(const float4*)(up[n] + (KO));                 \
            u##S[n * 2 + 1] = *(const float4*)(up[n] + (KO) + 4);             \
        }                                                                     \
    }

#define GU_STEP(S)                                                            \
    {                                                                         \
        bf16x8 bg[2], bu[2];                                                  \
        _Pragma("unroll")                                                     \
        for (int n = 0; n < 2; ++n) {                                         \
            bg[n] = pk8(g##S[n * 2], g##S[n * 2 + 1]);                        \
            bu[n] = pk8(u##S[n * 2], u##S[n * 2 + 1]);                        \
        }                                                                     \
        _Pragma("unroll")                                                     \
        for (int m = 0; m < 2; ++m)                                           \
            _Pragma("unroll")                                                 \
            for (int n = 0; n < 2; ++n) {                                     \
                accg[m][n] = __builtin_amdgcn_mfma_f32_16x16x32_bf16(a##S[m], bg[n], accg[m][n], 0, 0, 0); \
                accu[m][n] = __builtin_amdgcn_mfma_f32_16x16x32_bf16(a##S[m], bu[n], accu[m][n], 0, 0, 0); \
            }                                                                 \
    }

__global__ __launch_bounds__(64, 3) void gateup_mfma(
    const unsigned short* __restrict__ xb,
    const float* __restrict__ w_gate, const float* __restrict__ w_up,
    const int* __restrict__ count, const int* __restrict__ offsets,
    const int* __restrict__ worklist, const int* __restrict__ ntiles,
    const int* __restrict__ list_token, const float* __restrict__ list_w,
    unsigned short* __restrict__ h)
{
    if ((int)blockIdx.y >= ntiles[0]) return;
    const int wl = worklist[blockIdx.y];
    const int e  = wl >> 16;
    const int m0 = wl & 0xFFFF;
    const int f0 = blockIdx.x * 32;
    const int mc = min(32, count[e] - m0);

    const int lane = threadIdx.x;     // 0..63 (one wave)
    const int lr = lane & 15;
    const int kq = (lane >> 4) * 8;   // 8-elem k sub-window

    // A: token rows (bf16), lanes l, l+16, l+32, l+48 cover 64B of one row
    const unsigned short* aptr[2];
    #pragma unroll
    for (int m = 0; m < 2; ++m) {
        const int r = m * 16 + lr;
        const int t = list_token[e * BS + m0 + (r < mc ? r : 0)];
        aptr[m] = xb + (size_t)t * DIM + kq;
    }
    // B: f rows of w_gate / w_up (fp32)
    const float* gp[2];
    const float* up[2];
    #pragma unroll
    for (int n = 0; n < 2; ++n) {
        const int fr = f0 + n * 16 + lr;
        gp[n] = w_gate + (size_t)e * NF * DIM + (size_t)fr * DIM + kq;
        up[n] = w_up   + (size_t)e * NF * DIM + (size_t)fr * DIM + kq;
    }

    f32x4 accg[2][2] = {};
    f32x4 accu[2][2] = {};
    bf16x8 aE[2], aO[2];
    float4 gE[4], uE[4], gO[4], uO[4];

    GU_ISSUE(E, 0);
    __builtin_amdgcn_sched_barrier(0);
    for (int t = 0; t < DIM / 32; t += 2) {
        GU_ISSUE(O, (t + 1) * 32);
        __builtin_amdgcn_sched_barrier(0);
        GU_STEP(E);
        if (t + 2 < DIM / 32) {
            GU_ISSUE(E, (t + 2) * 32);
            __builtin_amdgcn_sched_barrier(0);
        }
        GU_STEP(O);
    }

    const int base = offsets[e] + m0;
    #pragma unroll
    for (int m = 0; m < 2; ++m) {
        #pragma unroll
        for (int j = 0; j < 4; ++j) {
            const int tl = m * 16 + (lane >> 4) * 4 + j;
            if (tl < mc) {
                const float w = list_w[e * BS + m0 + tl];
                #pragma unroll
                for (int n = 0; n < 2; ++n) {
                    const int fl = f0 + n * 16 + lr;
                    const float g  = accg[m][n][j];
                    const float u  = accu[m][n][j];
                    const float hv = w * u * (g / (1.f + __expf(-g)));
                    h[(size_t)(base + tl) * NF + fl] = f2bf(hv);
                }
            }
        }
    }
}

// ================= down: 1-wave blocks, direct-to-reg streaming MFMA + atomics =================
// wave tile = 32 slots x 32 d, BK=32 over F=512 (16 steps).

#define DK_ISSUE(S, KO)                                                       \
    {                                                                         \
        _Pragma("unroll")                                                     \
        for (int m = 0; m < 2; ++m) a##S[m] = *(const bf16x8*)(aptr[m] + (KO)); \
        _Pragma("unroll")                                                     \
        for (int n = 0; n < 2; ++n) {                                         \
            w##S[n * 2]     = *(const float4*)(bp[n] + (KO));                 \
            w##S[n * 2 + 1] = *(const float4*)(bp[n] + (KO) + 4);             \
        }                                                                     \
    }

#define DK_STEP(S)                                                            \
    {                                                                         \
        bf16x8 b[2];                                                          \
        _Pragma("unroll")                                                     \
        for (int n = 0; n < 2; ++n) b[n] = pk8(w##S[n * 2], w##S[n * 2 + 1]); \
        _Pragma("unroll")                                                     \
        for (int m = 0; m < 2; ++m)                                           \
            _Pragma("unroll")                                                 \
            for (int n = 0; n < 2; ++n)                                       \
                acc[m][n] = __builtin_amdgcn_mfma_f32_16x16x32_bf16(a##S[m], b[n], acc[m][n], 0, 0, 0); \
    }

__global__ __launch_bounds__(64, 4) void down_mfma(
    const float* __restrict__ w_down,
    const int* __restrict__ count, const int* __restrict__ offsets,
    const int* __restrict__ worklist, const int* __restrict__ ntiles,
    const int* __restrict__ list_token,
    const unsigned short* __restrict__ h, float* __restrict__ out)
{
    if ((int)blockIdx.y >= ntiles[0]) return;
    const int wl = worklist[blockIdx.y];
    const int e  = wl >> 16;
    const int m0 = wl & 0xFFFF;
    const int d0 = blockIdx.x * 32;
    const int mc = min(32, count[e] - m0);

    const int lane = threadIdx.x;
    const int lr = lane & 15;
    const int kq = (lane >> 4) * 8;
    const int base = offsets[e] + m0;

    // A: h slot rows (bf16)
    const unsigned short* aptr[2];
    #pragma unroll
    for (int m = 0; m < 2; ++m) {
        const int r = m * 16 + lr;
        aptr[m] = h + (size_t)(base + (r < mc ? r : 0)) * NF + kq;
    }
    // B: w_down d rows (fp32, row length NF)
    const float* bp[2];
    #pragma unroll
    for (int n = 0; n < 2; ++n) {
        const int dr = d0 + n * 16 + lr;
        bp[n] = w_down + (size_t)e * DIM * NF + (size_t)dr * NF + kq;
    }

    f32x4 acc[2][2] = {};
    bf16x8 aE[2], aO[2];
    float4 wE[4], wO[4];

    DK_ISSUE(E, 0);
    __builtin_amdgcn_sched_barrier(0);
    for (int t = 0; t < NF / 32; t += 2) {
        DK_ISSUE(O, (t + 1) * 32);
        __builtin_amdgcn_sched_barrier(0);
        DK_STEP(E);
        if (t + 2 < NF / 32) {
            DK_ISSUE(E, (t + 2) * 32);
            __builtin_amdgcn_sched_barrier(0);
        }
        DK_STEP(O);
    }

    #pragma unroll
    for (int m = 0; m < 2; ++m)
        #pragma unroll
        for (int j = 0; j < 4; ++j) {
            const int sl = m * 16 + (lane >> 4) * 4 + j;
            if (sl < mc) {
                const int tok = list_token[e * BS + m0 + sl];
                float* orow = out + (size_t)tok * DIM + d0 + lr;
                #pragma unroll
                for (int n = 0; n < 2; ++n)
                    atomicAdd(&orow[n * 16], acc[m][n][j]);
            }
        }
}

extern "C" void kernel_launch(void* const* d_in, const int* in_sizes, int n_in,
                              void* d_out, int out_size, void* d_ws, size_t ws_size,
                              hipStream_t stream)
{
    const float* x          = (const float*)d_in[0];
    const float* gate_w     = (const float*)d_in[1];
    const float* w_gate     = (const float*)d_in[2];
    const float* w_up       = (const float*)d_in[3];
    const float* w_down     = (const float*)d_in[4];
    const int*   token_mod  = (const int*)d_in[5];
    const int*   expert_mod = (const int*)d_in[6];
    float* out = (float*)d_out;

    // ws: h bf16 16 MB | x_bf16 8 MB | count | offsets | ntiles | worklist | list_token | list_w
    char* ws = (char*)d_ws;
    unsigned short* h  = (unsigned short*)ws;                       // 16,777,216 B
    unsigned short* xb = (unsigned short*)(ws + 16777216);          //  8,388,608 B
    int*   count      = (int*)(ws + 25165824);                      // 256 B
    int*   offsets    = (int*)(ws + 25166080);                      // 256 B
    int*   ntiles     = (int*)(ws + 25166336);                      // 256 B
    int*   worklist   = (int*)(ws + 25166592);                      // 4096 B
    int*   list_token = (int*)(ws + 25170688);                      // 524,288 B
    float* list_w     = (float*)(ws + 25694976);                    // 524,288 B

    zero_kernel<<<2048, 256, 0, stream>>>(out, count);
    cvt_x_kernel<<<1024, 256, 0, stream>>>(x, xb);
    router_kernel<<<BS / 4, 256, 0, stream>>>(x, gate_w, token_mod, expert_mod,
                                              count, list_token, list_w);
    scan_kernel<<<1, 64, 0, stream>>>(count, offsets, worklist, ntiles);

    dim3 g1(NF / 32, NT32);    // (16, 576) 1-wave blocks
    gateup_mfma<<<g1, 64, 0, stream>>>(xb, w_gate, w_up, count, offsets,
                                       worklist, ntiles, list_token, list_w, h);
    dim3 g2(DIM / 32, NT32);   // (64, 576) 1-wave blocks
    down_mfma<<<g2, 64, 0, stream>>>(w_down, count, offsets, worklist, ntiles,
                                     list_token, h, out);
}

// Round 12
// 783.549 us; speedup vs baseline: 1.7375x; 1.4390x over previous
//
#include <hip/hip_runtime.h>
#include <math.h>

#define BS   2048
#define DIM  2048
#define NE   64
#define NF   512
#define TOPK 8
#define MAXT 320   // max (expert, m0) 64-token tiles

typedef __attribute__((ext_vector_type(8))) short bf16x8;
typedef __attribute__((ext_vector_type(4))) float f32x4;

// pack 2 f32 -> 2 bf16 (RNE), lo in [15:0]
__device__ __forceinline__ unsigned cvt2(float lo, float hi) {
    unsigned r;
    asm("v_cvt_pk_bf16_f32 %0, %1, %2" : "=v"(r) : "v"(lo), "v"(hi));
    return r;
}
__device__ __forceinline__ unsigned short f2bf(float f) {
    return (unsigned short)(cvt2(f, 0.f) & 0xFFFF);
}

// async global -> LDS, 16B/lane; LDS dest = wave-uniform base + lane*16 (HW)
__device__ __forceinline__ void gll16(const void* g, void* l) {
    __builtin_amdgcn_global_load_lds(
        (const __attribute__((address_space(1))) void*)g,
        (__attribute__((address_space(3))) void*)l, 16, 0, 0);
}

// fragment (8 fp32 -> bf16x8) from fp32 LDS tile, 128-B rows, blk' = blk ^ (row&7)
__device__ __forceinline__ bf16x8 fragf32(const char* p, int row, int cb0) {
    const int sw = row & 7;
    const f32x4 lo = *(const f32x4*)(p + (row << 7) + ((cb0 ^ sw) << 4));
    const f32x4 hi = *(const f32x4*)(p + (row << 7) + (((cb0 + 1) ^ sw) << 4));
    union { bf16x8 v; unsigned u[4]; } r;
    r.u[0] = cvt2(lo[0], lo[1]);
    r.u[1] = cvt2(lo[2], lo[3]);
    r.u[2] = cvt2(hi[0], hi[1]);
    r.u[3] = cvt2(hi[2], hi[3]);
    return r.v;
}
// bf16 fragment from bf16 LDS tile, 64-B rows, blk' = blk ^ ((row>>1)&3)
__device__ __forceinline__ bf16x8 fragbf(const char* p, int row, int q) {
    return *(const bf16x8*)(p + (row << 6) + ((q ^ ((row >> 1) & 3)) << 4));
}

// ---------------- zero out + counters ----------------
__global__ __launch_bounds__(256) void zero_kernel(float* __restrict__ out, int* __restrict__ count)
{
    const size_t idx = (size_t)blockIdx.x * blockDim.x + threadIdx.x;
    const size_t tot = (size_t)BS * DIM;
    for (size_t i = idx * 4; i < tot; i += (size_t)gridDim.x * blockDim.x * 4) {
        *(float4*)&out[i] = make_float4(0.f, 0.f, 0.f, 0.f);
    }
    if (idx < NE) count[idx] = 0;
}

// ---------------- x fp32 -> bf16 (8.4 MB, L3-resident working copy) ----------------
__global__ __launch_bounds__(256) void cvt_x_kernel(const float* __restrict__ x,
                                                    unsigned short* __restrict__ xb)
{
    const int idx = blockIdx.x * 256 + threadIdx.x;
    const int tot = BS * DIM / 4;
    for (int i = idx; i < tot; i += gridDim.x * 256) {
        const float4 v = *(const float4*)&x[i * 4];
        *(uint2*)&xb[i * 4] = make_uint2(cvt2(v.x, v.y), cvt2(v.z, v.w));
    }
}

// ---------------- router: 4 tokens/block, wave-parallel top-8 ----------------
__global__ __launch_bounds__(256) void router_kernel(
    const float* __restrict__ x, const float* __restrict__ gate_w,
    const int* __restrict__ token_mod, const int* __restrict__ expert_mod,
    int* __restrict__ count, int* __restrict__ list_token, float* __restrict__ list_w)
{
    __shared__ float xs[4 * DIM];
    __shared__ float pr[4][NE];
    const int t0  = blockIdx.x * 4;
    const int tid = threadIdx.x;
    const int lane = tid & 63, wave = tid >> 6;

    float4* xs4 = (float4*)xs;
    const float4* xr = (const float4*)(x + (size_t)t0 * DIM);
    for (int i = tid; i < 4 * (DIM / 4); i += 256) xs4[i] = xr[i];
    __syncthreads();

    for (int j = 0; j < 16; ++j) {
        const int e = wave * 16 + j;
        const float4* gw = (const float4*)(gate_w + (size_t)e * DIM);
        float s0 = 0.f, s1 = 0.f, s2 = 0.f, s3 = 0.f;
        for (int i = lane; i < DIM / 4; i += 64) {
            const float4 g  = gw[i];
            const float4 v0 = xs4[0 * 512 + i];
            const float4 v1 = xs4[1 * 512 + i];
            const float4 v2 = xs4[2 * 512 + i];
            const float4 v3 = xs4[3 * 512 + i];
            s0 += v0.x * g.x + v0.y * g.y + v0.z * g.z + v0.w * g.w;
            s1 += v1.x * g.x + v1.y * g.y + v1.z * g.z + v1.w * g.w;
            s2 += v2.x * g.x + v2.y * g.y + v2.z * g.z + v2.w * g.w;
            s3 += v3.x * g.x + v3.y * g.y + v3.z * g.z + v3.w * g.w;
        }
        #pragma unroll
        for (int off = 32; off > 0; off >>= 1) {
            s0 += __shfl_xor(s0, off, 64);
            s1 += __shfl_xor(s1, off, 64);
            s2 += __shfl_xor(s2, off, 64);
            s3 += __shfl_xor(s3, off, 64);
        }
        if (lane == 0) {
            pr[0][e] = s0; pr[1][e] = s1; pr[2][e] = s2; pr[3][e] = s3;
        }
    }
    __syncthreads();

    {
        const int t  = t0 + wave;
        const int tm = token_mod[t];
        const int em = expert_mod[lane];
        float p = pr[wave][lane];
        if (tm * em == -1) p = -INFINITY;
        float m0 = p;
        #pragma unroll
        for (int off = 32; off > 0; off >>= 1) m0 = fmaxf(m0, __shfl_xor(m0, off, 64));
        p = __expf(p - m0);                  // exp(-inf)=0; softmax denom cancels in renorm
        float s8 = 0.f, wsel = 0.f;
        int   esel = 0;
        #pragma unroll
        for (int k = 0; k < TOPK; ++k) {
            float m = p;
            #pragma unroll
            for (int off = 32; off > 0; off >>= 1) m = fmaxf(m, __shfl_xor(m, off, 64));
            const unsigned long long b = __ballot(p == m);
            const int bi = __ffsll((unsigned long long)b) - 1;   // lowest index on ties
            if (lane == bi) p = -1.f;
            if (lane == k) { esel = bi; wsel = m; }
            s8 += m;
        }
        const float inv = 1.f / s8;
        if (lane < TOPK) {
            const int pos = atomicAdd(&count[esel], 1);
            list_token[esel * BS + pos] = t;
            list_w[esel * BS + pos]     = wsel * inv;
        }
    }
}

// ---------------- scan + compacted (expert, m0) 64-token worklist ----------------
__global__ void scan_kernel(const int* __restrict__ count, int* __restrict__ offsets,
                            int* __restrict__ worklist, int* __restrict__ ntiles)
{
    if (threadIdx.x == 0) {
        int s = 0, nt = 0;
        for (int e = 0; e < NE; ++e) {
            offsets[e] = s;
            for (int m0 = 0; m0 < count[e]; m0 += 64) worklist[nt++] = (e << 16) | m0;
            s += count[e];
        }
        ntiles[0] = nt;
    }
}

// ================= gate/up: gll 3-stage pipeline, counted vmcnt =================
// block 64 tok x 64 f, BK=32, 64 steps, 4 waves (wave = 32tok x 32f, gate+up).
// Stage 20KB: X bf16 4K | G fp32 8K | U fp32 8K. 3 stages = 60KB -> 2 blocks/CU.
// 5 glls/wave/stage; steady wait vmcnt(10) = 2 stages in flight (T4, never 0 mid-loop).
#define GU_ST   20480
#define GU_XO   0
#define GU_GO   4096
#define GU_UO   12288
#define GU_NST  64

#define GU_ISSUE(T, SB)                                                      \
    {                                                                        \
        gll16(xsrc + (T) * 32, &lds[(SB) + xdo]);                            \
        gll16(gsrc0 + (T) * 32, &lds[(SB) + gdo]);                           \
        gll16(gsrc1 + (T) * 32, &lds[(SB) + gdo + 1024]);                    \
        gll16(usrc0 + (T) * 32, &lds[(SB) + udo]);                           \
        gll16(usrc1 + (T) * 32, &lds[(SB) + udo + 1024]);                    \
    }

#define GU_COMPUTE(SB)                                                       \
    {                                                                        \
        const char* Bp = &lds[(SB)];                                         \
        bf16x8 bx[2], ag[2], au[2];                                          \
        _Pragma("unroll")                                                    \
        for (int nt = 0; nt < 2; ++nt)                                       \
            bx[nt] = fragbf(Bp + GU_XO, wr * 32 + nt * 16 + (lane & 15), lane >> 4); \
        _Pragma("unroll")                                                    \
        for (int mm = 0; mm < 2; ++mm) {                                     \
            const int r = wc * 32 + mm * 16 + (lane & 15);                   \
            ag[mm] = fragf32(Bp + GU_GO, r, (lane >> 4) * 2);                \
            au[mm] = fragf32(Bp + GU_UO, r, (lane >> 4) * 2);                \
        }                                                                    \
        _Pragma("unroll")                                                    \
        for (int mm = 0; mm < 2; ++mm)                                       \
            _Pragma("unroll")                                                \
            for (int nt = 0; nt < 2; ++nt) {                                 \
                accg[mm][nt] = __builtin_amdgcn_mfma_f32_16x16x32_bf16(ag[mm], bx[nt], accg[mm][nt], 0, 0, 0); \
                accu[mm][nt] = __builtin_amdgcn_mfma_f32_16x16x32_bf16(au[mm], bx[nt], accu[mm][nt], 0, 0, 0); \
            }                                                                \
    }

__global__ __launch_bounds__(256, 2) void gateup_mfma(
    const unsigned short* __restrict__ xb,
    const float* __restrict__ w_gate, const float* __restrict__ w_up,
    const int* __restrict__ count, const int* __restrict__ offsets,
    const int* __restrict__ worklist, const int* __restrict__ ntiles,
    const int* __restrict__ list_token, const float* __restrict__ list_w,
    unsigned short* __restrict__ h)
{
    if ((int)blockIdx.y >= ntiles[0]) return;
    const int wl = worklist[blockIdx.y];
    const int e  = wl >> 16;
    const int m0 = wl & 0xFFFF;
    const int f0 = blockIdx.x * 64;
    const int mc = min(64, count[e] - m0);

    __shared__ char lds[3 * GU_ST];

    const int tid = threadIdx.x;
    const int lane = tid & 63, wave = tid >> 6;
    const int wr = wave >> 1, wc = wave & 1;

    // staging sources: linear LDS dest + inverse-swizzled GLOBAL source (rule #21)
    const int xr  = wave * 16 + (lane >> 2);
    const int xbk = (lane & 3) ^ ((xr >> 1) & 3);
    const unsigned short* xsrc =
        xb + (size_t)list_token[e * BS + m0 + (xr < mc ? xr : 0)] * DIM + xbk * 8;

    const int gr0  = wave * 16 + (lane >> 3);
    const int gr1  = gr0 + 8;
    const int gbk0 = (lane & 7) ^ (gr0 & 7);
    const int gbk1 = (lane & 7) ^ (gr1 & 7);
    const float* gsrc0 = w_gate + (size_t)e * NF * DIM + (size_t)(f0 + gr0) * DIM + gbk0 * 4;
    const float* gsrc1 = w_gate + (size_t)e * NF * DIM + (size_t)(f0 + gr1) * DIM + gbk1 * 4;
    const float* usrc0 = w_up   + (size_t)e * NF * DIM + (size_t)(f0 + gr0) * DIM + gbk0 * 4;
    const float* usrc1 = w_up   + (size_t)e * NF * DIM + (size_t)(f0 + gr1) * DIM + gbk1 * 4;

    const int xdo = GU_XO + wave * 1024;   // wave-uniform dests (HW adds lane*16)
    const int gdo = GU_GO + wave * 2048;
    const int udo = GU_UO + wave * 2048;

    f32x4 accg[2][2] = {};
    f32x4 accu[2][2] = {};

    GU_ISSUE(0, 0);
    GU_ISSUE(1, GU_ST);
    GU_ISSUE(2, 2 * GU_ST);

    int sb = 0;
    for (int t = 0; t < GU_NST; ++t) {
        if (t < GU_NST - 2)       { asm volatile("s_waitcnt vmcnt(10)" ::: "memory"); }
        else if (t == GU_NST - 2) { asm volatile("s_waitcnt vmcnt(5)"  ::: "memory"); }
        else                      { asm volatile("s_waitcnt vmcnt(0)"  ::: "memory"); }
        __builtin_amdgcn_sched_barrier(0);
        __builtin_amdgcn_s_barrier();          // all waves' stage-t glls landed
        __builtin_amdgcn_sched_barrier(0);
        GU_COMPUTE(sb);
        __builtin_amdgcn_sched_barrier(0);
        __builtin_amdgcn_s_barrier();          // all reads of this slot done
        __builtin_amdgcn_sched_barrier(0);
        if (t + 3 < GU_NST) GU_ISSUE(t + 3, sb);
        sb = (sb == 2 * GU_ST) ? 0 : sb + GU_ST;
    }

    const int base = offsets[e] + m0;
    #pragma unroll
    for (int mm = 0; mm < 2; ++mm)
        #pragma unroll
        for (int nt = 0; nt < 2; ++nt) {
            const int tl = wr * 32 + nt * 16 + (lane & 15);
            if (tl < mc) {
                const float w = list_w[e * BS + m0 + tl];
                float hv[4];
                #pragma unroll
                for (int j = 0; j < 4; ++j) {
                    const float g = accg[mm][nt][j];
                    const float u = accu[mm][nt][j];
                    hv[j] = w * u * (g / (1.f + __expf(-g)));
                }
                const int fl = f0 + wc * 32 + mm * 16 + (lane >> 4) * 4;
                *(uint2*)&h[(size_t)(base + tl) * NF + fl] =
                    make_uint2(cvt2(hv[0], hv[1]), cvt2(hv[2], hv[3]));
            }
        }
}

// ================= down: gll 3-stage pipeline + atomic combine =================
// block 64 slots x 128 d, BK=32 over F=512, 16 steps. wave = 32 slots x 64 d.
// Stage 20KB: H bf16 4K | W fp32 16K. 3 stages = 60KB. 5 glls/wave/stage.
#define DK_ST   20480
#define DK_HO   0
#define DK_WO   4096
#define DK_NST  16

#define DK_ISSUE(T, SB)                                                      \
    {                                                                        \
        gll16(hsrc + (T) * 32, &lds[(SB) + hdo]);                            \
        gll16(wsrc0 + (T) * 32, &lds[(SB) + wdo]);                           \
        gll16(wsrc1 + (T) * 32, &lds[(SB) + wdo + 1024]);                    \
        gll16(wsrc2 + (T) * 32, &lds[(SB) + wdo + 2048]);                    \
        gll16(wsrc3 + (T) * 32, &lds[(SB) + wdo + 3072]);                    \
    }

#define DK_COMPUTE(SB)                                                       \
    {                                                                        \
        const char* Bp = &lds[(SB)];                                         \
        bf16x8 bh[2], aw[4];                                                 \
        _Pragma("unroll")                                                    \
        for (int nt = 0; nt < 2; ++nt)                                       \
            bh[nt] = fragbf(Bp + DK_HO, wr * 32 + nt * 16 + (lane & 15), lane >> 4); \
        _Pragma("unroll")                                                    \
        for (int dd = 0; dd < 4; ++dd)                                       \
            aw[dd] = fragf32(Bp + DK_WO, wc * 64 + dd * 16 + (lane & 15), (lane >> 4) * 2); \
        _Pragma("unroll")                                                    \
        for (int dd = 0; dd < 4; ++dd)                                       \
            _Pragma("unroll")                                                \
            for (int nt = 0; nt < 2; ++nt)                                   \
                acc[dd][nt] = __builtin_amdgcn_mfma_f32_16x16x32_bf16(aw[dd], bh[nt], acc[dd][nt], 0, 0, 0); \
    }

__global__ __launch_bounds__(256, 2) void down_mfma(
    const float* __restrict__ w_down,
    const int* __restrict__ count, const int* __restrict__ offsets,
    const int* __restrict__ worklist, const int* __restrict__ ntiles,
    const int* __restrict__ list_token,
    const unsigned short* __restrict__ h, float* __restrict__ out)
{
    if ((int)blockIdx.y >= ntiles[0]) return;
    const int wl = worklist[blockIdx.y];
    const int e  = wl >> 16;
    const int m0 = wl & 0xFFFF;
    const int d0 = blockIdx.x * 128;
    const int mc = min(64, count[e] - m0);

    __shared__ char lds[3 * DK_ST];

    const int tid = threadIdx.x;
    const int lane = tid & 63, wave = tid >> 6;
    const int wr = wave >> 1, wc = wave & 1;
    const int base = offsets[e] + m0;

    const int hr  = wave * 16 + (lane >> 2);
    const int hbk = (lane & 3) ^ ((hr >> 1) & 3);
    const unsigned short* hsrc =
        h + (size_t)(base + (hr < mc ? hr : 0)) * NF + hbk * 8;

    const float* wd = w_down + (size_t)e * DIM * NF;
    const int wrr0 = wave * 32 + (lane >> 3);
    const float* wsrc0 = wd + (size_t)(d0 + wrr0)      * NF + (((lane & 7) ^ ( wrr0       & 7)) * 4);
    const float* wsrc1 = wd + (size_t)(d0 + wrr0 + 8)  * NF + (((lane & 7) ^ ((wrr0 + 8)  & 7)) * 4);
    const float* wsrc2 = wd + (size_t)(d0 + wrr0 + 16) * NF + (((lane & 7) ^ ((wrr0 + 16) & 7)) * 4);
    const float* wsrc3 = wd + (size_t)(d0 + wrr0 + 24) * NF + (((lane & 7) ^ ((wrr0 + 24) & 7)) * 4);

    const int hdo = DK_HO + wave * 1024;
    const int wdo = DK_WO + wave * 4096;

    f32x4 acc[4][2] = {};

    DK_ISSUE(0, 0);
    DK_ISSUE(1, DK_ST);
    DK_ISSUE(2, 2 * DK_ST);

    int sb = 0;
    for (int t = 0; t < DK_NST; ++t) {
        if (t < DK_NST - 2)       { asm volatile("s_waitcnt vmcnt(10)" ::: "memory"); }
        else if (t == DK_NST - 2) { asm volatile("s_waitcnt vmcnt(5)"  ::: "memory"); }
        else                      { asm volatile("s_waitcnt vmcnt(0)"  ::: "memory"); }
        __builtin_amdgcn_sched_barrier(0);
        __builtin_amdgcn_s_barrier();
        __builtin_amdgcn_sched_barrier(0);
        DK_COMPUTE(sb);
        __builtin_amdgcn_sched_barrier(0);
        __builtin_amdgcn_s_barrier();
        __builtin_amdgcn_sched_barrier(0);
        if (t + 3 < DK_NST) DK_ISSUE(t + 3, sb);
        sb = (sb == 2 * DK_ST) ? 0 : sb + DK_ST;
    }

    #pragma unroll
    for (int dd = 0; dd < 4; ++dd)
        #pragma unroll
        for (int nt = 0; nt < 2; ++nt) {
            const int tl = wr * 32 + nt * 16 + (lane & 15);
            if (tl < mc) {
                const int tok = list_token[e * BS + m0 + tl];
                float* orow = out + (size_t)tok * DIM + d0 + wc * 64 + dd * 16 + (lane >> 4) * 4;
                #pragma unroll
                for (int j = 0; j < 4; ++j)
                    atomicAdd(&orow[j], acc[dd][nt][j]);
            }
        }
}

extern "C" void kernel_launch(void* const* d_in, const int* in_sizes, int n_in,
                              void* d_out, int out_size, void* d_ws, size_t ws_size,
                              hipStream_t stream)
{
    const float* x          = (const float*)d_in[0];
    const float* gate_w     = (const float*)d_in[1];
    const float* w_gate     = (const float*)d_in[2];
    const float* w_up       = (const float*)d_in[3];
    const float* w_down     = (const float*)d_in[4];
    const int*   token_mod  = (const int*)d_in[5];
    const int*   expert_mod = (const int*)d_in[6];
    float* out = (float*)d_out;

    // ws: h bf16 16 MB | x_bf16 8 MB | count | offsets | ntiles | worklist | list_token | list_w
    char* ws = (char*)d_ws;
    unsigned short* h  = (unsigned short*)ws;                       // 16,777,216 B
    unsigned short* xb = (unsigned short*)(ws + 16777216);          //  8,388,608 B
    int*   count      = (int*)(ws + 25165824);                      // 256 B
    int*   offsets    = (int*)(ws + 25166080);                      // 256 B
    int*   ntiles     = (int*)(ws + 25166336);                      // 256 B
    int*   worklist   = (int*)(ws + 25166592);                      // 2048 B
    int*   list_token = (int*)(ws + 25168640);                      // 524,288 B
    float* list_w     = (float*)(ws + 25692928);                    // 524,288 B

    zero_kernel<<<2048, 256, 0, stream>>>(out, count);
    cvt_x_kernel<<<1024, 256, 0, stream>>>(x, xb);
    router_kernel<<<BS / 4, 256, 0, stream>>>(x, gate_w, token_mod, expert_mod,
                                              count, list_token, list_w);
    scan_kernel<<<1, 64, 0, stream>>>(count, offsets, worklist, ntiles);

    dim3 g1(NF / 64, MAXT);    // (8, 320)
    gateup_mfma<<<g1, 256, 0, stream>>>(xb, w_gate, w_up, count, offsets,
                                        worklist, ntiles, list_token, list_w, h);
    dim3 g2(DIM / 128, MAXT);  // (16, 320)
    down_mfma<<<g2, 256, 0, stream>>>(w_down, count, offsets, worklist, ntiles,
                                      list_token, h, out);
}